// Round 1
// baseline (1104.224 us; speedup 1.0000x reference)
//
#include <hip/hip_runtime.h>
#include <math.h>

// S4D block, MI355X. B=8, H=256, T=8192, N=16 complex states.
// WS layout (needs >= ~136MB):
//   [0)          SSM params P: 6*4096 floats (ar, ai, 2Cr, 2Ci, aL_r, aL_i)
//   [1MB)        mu1 (B*T f32), rs1, mu2, rs2  (256KB each)
//   [8MB)        S0: 64MB activation slot
//   [72MB)       S1: 64MB activation slot

#define TN 8192
#define HN 256
#define BN 8
#define NS 16

__device__ __forceinline__ float gelu_f(float v) {
    return 0.5f * v * (1.f + erff(v * 0.70710678118654752440f));
}
__device__ __forceinline__ float sigm_f(float v) {
    return 1.f / (1.f + expf(-v));
}

// ---------------- SSM constant prep: 4096 threads ----------------
__global__ void prep_kernel(const float* __restrict__ log_dt,
                            const float* __restrict__ C_re,
                            const float* __restrict__ C_im,
                            const float* __restrict__ log_A_real,
                            const float* __restrict__ A_imag,
                            float* __restrict__ P)
{
    int i = blockIdx.x * 64 + threadIdx.x;   // 0..4095
    int h = i >> 4;
    float dt = expf(log_dt[h]);
    float Ar = -expf(log_A_real[i]);
    float Ai = A_imag[i];
    // a = exp(dt*A)
    float er = expf(Ar * dt);
    float ar = er * cosf(Ai * dt);
    float ai = er * sinf(Ai * dt);
    // Cmod = (C_re + i C_im) * (a - 1) / A
    float Er = ar - 1.f, Ei = ai;
    float inv = 1.f / (Ar * Ar + Ai * Ai);
    float Fr = (Er * Ar + Ei * Ai) * inv;
    float Fi = (Ei * Ar - Er * Ai) * inv;
    float cr = C_re[i] * Fr - C_im[i] * Fi;
    float ci = C_re[i] * Fi + C_im[i] * Fr;
    // aL = a^128 (7 squarings)
    float pr = ar, pi = ai;
    #pragma unroll
    for (int s = 0; s < 7; ++s) { float t2 = pr * pr - pi * pi; pi = 2.f * pr * pi; pr = t2; }
    P[i]           = ar;
    P[4096 + i]    = ai;
    P[2*4096 + i]  = 2.f * cr;
    P[3*4096 + i]  = 2.f * ci;
    P[4*4096 + i]  = pr;
    P[5*4096 + i]  = pi;
}

// ---------------- channel-LN stats: mu/rstd per (b,t) ----------------
__global__ __launch_bounds__(256) void ln_stats_kernel(const float* __restrict__ X,
                                                       float* __restrict__ mu,
                                                       float* __restrict__ rs)
{
    int b = blockIdx.y;
    int t = blockIdx.x * 256 + threadIdx.x;
    const float* p = X + (size_t)b * HN * TN + t;
    float s = 0.f, ss = 0.f;
    #pragma unroll 8
    for (int c = 0; c < HN; ++c) {
        float v = p[(size_t)c * TN];
        s += v; ss += v * v;
    }
    float m = s * (1.f / HN);
    float var = ss * (1.f / HN) - m * m;
    mu[b * TN + t] = m;
    rs[b * TN + t] = rsqrtf(var + 1e-5f);
}

// ---------------- S4D recurrence scan (LN1 applied inline) ----------------
// One wave per (b,h). Lane l owns chunk [l*128, (l+1)*128).
// Phase1: local scan from 0.  Wave-scan (Hillis-Steele, uniform decay a^(128d)).
// Phase2: re-scan with correct init, emit gelu(u + D*y).
__global__ __launch_bounds__(256) void scan_kernel(const float* __restrict__ X,
                                                   const float* __restrict__ mu,
                                                   const float* __restrict__ rs,
                                                   const float* __restrict__ g1,
                                                   const float* __restrict__ b1,
                                                   const float* __restrict__ Dp,
                                                   const float* __restrict__ P,
                                                   float* __restrict__ GU)
{
    int wid  = (blockIdx.x << 2) + (threadIdx.x >> 6);  // 0..2047
    int lane = threadIdx.x & 63;
    int b = wid >> 8, h = wid & 255;

    float ar[NS], ai[NS];
    #pragma unroll
    for (int n = 0; n < NS; ++n) {
        int idx = h * NS + n;
        ar[n] = P[idx];
        ai[n] = P[4096 + idx];
    }
    float gh = g1[h], bh = b1[h];

    const float* xrow = X + (size_t)(b * HN + h) * TN;
    const float* mup  = mu + b * TN;
    const float* rsp  = rs + b * TN;
    int t0 = lane * 128;

    float sr[NS], si[NS];
    #pragma unroll
    for (int n = 0; n < NS; ++n) { sr[n] = 0.f; si[n] = 0.f; }

    // phase 1: local chunk scan
    for (int j = 0; j < 128; j += 4) {
        float4 xv = *(const float4*)(xrow + t0 + j);
        float4 m4 = *(const float4*)(mup + t0 + j);
        float4 r4 = *(const float4*)(rsp + t0 + j);
        float ys[4];
        ys[0] = fmaf((xv.x - m4.x) * r4.x, gh, bh);
        ys[1] = fmaf((xv.y - m4.y) * r4.y, gh, bh);
        ys[2] = fmaf((xv.z - m4.z) * r4.z, gh, bh);
        ys[3] = fmaf((xv.w - m4.w) * r4.w, gh, bh);
        #pragma unroll
        for (int e = 0; e < 4; ++e) {
            float y = ys[e];
            #pragma unroll
            for (int n = 0; n < NS; ++n) {
                float nr = fmaf(ar[n], sr[n], fmaf(-ai[n], si[n], y));
                float ni = fmaf(ar[n], si[n], ai[n] * sr[n]);
                sr[n] = nr; si[n] = ni;
            }
        }
    }

    // wave scan over chunk affine maps.  Decay for shift d is uniform: a^(128*d).
    float pdr[NS], pdi[NS];
    #pragma unroll
    for (int n = 0; n < NS; ++n) {
        int idx = h * NS + n;
        pdr[n] = P[4*4096 + idx];
        pdi[n] = P[5*4096 + idx];
    }
    #pragma unroll
    for (int d = 1; d < 64; d <<= 1) {
        #pragma unroll
        for (int n = 0; n < NS; ++n) {
            float qpr = __shfl_up(sr[n], (unsigned)d, 64);
            float qpi = __shfl_up(si[n], (unsigned)d, 64);
            if (lane >= d) {
                float nqr = fmaf(pdr[n], qpr, fmaf(-pdi[n], qpi, sr[n]));
                float nqi = fmaf(pdr[n], qpi, fmaf(pdi[n], qpr, si[n]));
                sr[n] = nqr; si[n] = nqi;
            }
        }
        #pragma unroll
        for (int n = 0; n < NS; ++n) {   // pd = pd^2 for next shift
            float t2 = pdr[n] * pdr[n] - pdi[n] * pdi[n];
            pdi[n] = 2.f * pdr[n] * pdi[n];
            pdr[n] = t2;
        }
    }
    // init state for my chunk = inclusive result of lane-1
    #pragma unroll
    for (int n = 0; n < NS; ++n) {
        float ir = __shfl_up(sr[n], 1u, 64);
        float ii = __shfl_up(si[n], 1u, 64);
        sr[n] = (lane == 0) ? 0.f : ir;
        si[n] = (lane == 0) ? 0.f : ii;
    }

    // phase 2: re-scan with init; emit gelu(u)
    float c2r[NS], c2i[NS];
    #pragma unroll
    for (int n = 0; n < NS; ++n) {
        int idx = h * NS + n;
        c2r[n] = P[2*4096 + idx];
        c2i[n] = P[3*4096 + idx];
    }
    float dh = Dp[h];
    float* gout = GU + (size_t)(b * HN + h) * TN;
    for (int j = 0; j < 128; j += 4) {
        float4 xv = *(const float4*)(xrow + t0 + j);
        float4 m4 = *(const float4*)(mup + t0 + j);
        float4 r4 = *(const float4*)(rsp + t0 + j);
        float ys[4];
        ys[0] = fmaf((xv.x - m4.x) * r4.x, gh, bh);
        ys[1] = fmaf((xv.y - m4.y) * r4.y, gh, bh);
        ys[2] = fmaf((xv.z - m4.z) * r4.z, gh, bh);
        ys[3] = fmaf((xv.w - m4.w) * r4.w, gh, bh);
        float ov[4];
        #pragma unroll
        for (int e = 0; e < 4; ++e) {
            float y = ys[e];
            float u = dh * y;
            #pragma unroll
            for (int n = 0; n < NS; ++n) {
                float nr = fmaf(ar[n], sr[n], fmaf(-ai[n], si[n], y));
                float ni = fmaf(ar[n], si[n], ai[n] * sr[n]);
                sr[n] = nr; si[n] = ni;
                u = fmaf(c2r[n], nr, fmaf(-c2i[n], ni, u));
            }
            ov[e] = gelu_f(u);
        }
        float4 o4 = make_float4(ov[0], ov[1], ov[2], ov[3]);
        *(float4*)(gout + t0 + j) = o4;
    }
}

// ---------------- fused conv1x1 (per-timestep GEMM) ----------------
// out[b,m,t] = epilogue( sum_k W[m,k]*in[b,k,t] + bias[m] )
// GLU:     W has 2*256 rows; out = (a+ba)*sigmoid(g+bg), rows paired (m, m+256)
// CONCAT:  K=512; k<256 from in0(x), k>=256 from in1(y3)
// LN_IN:   input element LN'd on the fly: (v-mu[b,t])*rs[b,t]*lng[k]+lnb[k]
// GELU_OUT: erf-gelu on the result;  ADD_RES: out += res[b,m,t]
template<int K, bool GLU, bool CONCAT, bool LN_IN, bool GELU_OUT, bool ADD_RES>
__global__ __launch_bounds__(256) void conv1x1_kernel(
    const float* __restrict__ in0, const float* __restrict__ in1,
    const float* __restrict__ W, const float* __restrict__ bias,
    const float* __restrict__ lnmu, const float* __restrict__ lnrs,
    const float* __restrict__ lng, const float* __restrict__ lnb,
    const float* __restrict__ res, float* __restrict__ out)
{
    constexpr int MT = 64, NT = 128, KT = 16;
    __shared__ float sA[KT][MT];
    __shared__ float sG[GLU ? KT : 1][MT];
    __shared__ float sI[KT][NT];

    int b  = blockIdx.z;
    int t0 = blockIdx.x * NT;
    int m0 = blockIdx.y * MT;
    int tid = threadIdx.x;
    int ty = tid >> 4;   // 0..15 -> rows m0+ty*4..+3
    int tx = tid & 15;   // cols t0+tx*8..+7

    float acc[4][8];
    #pragma unroll
    for (int i = 0; i < 4; ++i)
        #pragma unroll
        for (int j = 0; j < 8; ++j) acc[i][j] = 0.f;
    float accg[GLU ? 4 : 1][GLU ? 8 : 1];
    if constexpr (GLU) {
        #pragma unroll
        for (int i = 0; i < 4; ++i)
            #pragma unroll
            for (int j = 0; j < 8; ++j) accg[i][j] = 0.f;
    }

    int wr = tid >> 2;          // 0..63  (W tile row)
    int wc = (tid & 3) << 2;    // 0,4,8,12 (W tile col, float4)

    for (int k0 = 0; k0 < K; k0 += KT) {
        // --- stage W tiles (transposed into [k][m]) ---
        {
            float4 wv = *(const float4*)&W[(size_t)(m0 + wr) * K + k0 + wc];
            sA[wc + 0][wr] = wv.x; sA[wc + 1][wr] = wv.y;
            sA[wc + 2][wr] = wv.z; sA[wc + 3][wr] = wv.w;
            if constexpr (GLU) {
                float4 wg = *(const float4*)&W[(size_t)(m0 + 256 + wr) * K + k0 + wc];
                sG[wc + 0][wr] = wg.x; sG[wc + 1][wr] = wg.y;
                sG[wc + 2][wr] = wg.z; sG[wc + 3][wr] = wg.w;
            }
        }
        // --- stage input tile [k][t] ---
        #pragma unroll
        for (int it = 0; it < 2; ++it) {
            int idx = tid + it * 256;        // 0..511
            int kk = idx >> 5;               // 0..15
            int tc = (idx & 31) << 2;        // 0..124
            int kg = k0 + kk;
            const float* src;
            if constexpr (CONCAT)
                src = (kg < 256) ? (in0 + (size_t)(b * HN + kg) * TN)
                                 : (in1 + (size_t)(b * HN + (kg - 256)) * TN);
            else
                src = in0 + (size_t)(b * HN + kg) * TN;
            float4 v = *(const float4*)(src + t0 + tc);
            if constexpr (LN_IN) {
                float4 m4 = *(const float4*)(lnmu + b * TN + t0 + tc);
                float4 r4 = *(const float4*)(lnrs + b * TN + t0 + tc);
                float gk = lng[kg], bk = lnb[kg];
                v.x = fmaf((v.x - m4.x) * r4.x, gk, bk);
                v.y = fmaf((v.y - m4.y) * r4.y, gk, bk);
                v.z = fmaf((v.z - m4.z) * r4.z, gk, bk);
                v.w = fmaf((v.w - m4.w) * r4.w, gk, bk);
            }
            *(float4*)&sI[kk][tc] = v;
        }
        __syncthreads();

        #pragma unroll
        for (int kk = 0; kk < KT; ++kk) {
            float av[4], bv[8];
            *(float4*)av = *(const float4*)&sA[kk][ty << 2];
            *(float4*)(bv)     = *(const float4*)&sI[kk][tx << 3];
            *(float4*)(bv + 4) = *(const float4*)&sI[kk][(tx << 3) + 4];
            #pragma unroll
            for (int i = 0; i < 4; ++i)
                #pragma unroll
                for (int j = 0; j < 8; ++j)
                    acc[i][j] = fmaf(av[i], bv[j], acc[i][j]);
            if constexpr (GLU) {
                float gv[4];
                *(float4*)gv = *(const float4*)&sG[kk][ty << 2];
                #pragma unroll
                for (int i = 0; i < 4; ++i)
                    #pragma unroll
                    for (int j = 0; j < 8; ++j)
                        accg[i][j] = fmaf(gv[i], bv[j], accg[i][j]);
            }
        }
        __syncthreads();
    }

    // --- epilogue ---
    #pragma unroll
    for (int i = 0; i < 4; ++i) {
        int m = m0 + (ty << 2) + i;
        float ba = bias[m];
        float vv[8];
        #pragma unroll
        for (int j = 0; j < 8; ++j) {
            float v = acc[i][j] + ba;
            if constexpr (GLU) {
                float g = accg[i][j] + bias[m + 256];
                v = v * sigm_f(g);
            }
            if constexpr (GELU_OUT) v = gelu_f(v);
            vv[j] = v;
        }
        size_t ro = (size_t)(b * HN + m) * TN + t0 + (tx << 3);
        if constexpr (ADD_RES) {
            float4 r0 = *(const float4*)(res + ro);
            float4 r1 = *(const float4*)(res + ro + 4);
            vv[0] += r0.x; vv[1] += r0.y; vv[2] += r0.z; vv[3] += r0.w;
            vv[4] += r1.x; vv[5] += r1.y; vv[6] += r1.z; vv[7] += r1.w;
        }
        float4 o0 = make_float4(vv[0], vv[1], vv[2], vv[3]);
        float4 o1 = make_float4(vv[4], vv[5], vv[6], vv[7]);
        *(float4*)(out + ro)     = o0;
        *(float4*)(out + ro + 4) = o1;
    }
}

extern "C" void kernel_launch(void* const* d_in, const int* in_sizes, int n_in,
                              void* d_out, int out_size, void* d_ws, size_t ws_size,
                              hipStream_t stream)
{
    (void)in_sizes; (void)n_in; (void)out_size; (void)ws_size;
    const float* x      = (const float*)d_in[0];
    const float* log_dt = (const float*)d_in[1];
    const float* C_re   = (const float*)d_in[2];
    const float* C_im   = (const float*)d_in[3];
    const float* logAr  = (const float*)d_in[4];
    const float* A_im   = (const float*)d_in[5];
    const float* Dp     = (const float*)d_in[6];
    const float* outW   = (const float*)d_in[7];
    const float* outB   = (const float*)d_in[8];
    const float* ln1g   = (const float*)d_in[9];
    const float* ln1b   = (const float*)d_in[10];
    const float* lin1W  = (const float*)d_in[11];
    const float* lin1b  = (const float*)d_in[12];
    const float* gluW   = (const float*)d_in[13];
    const float* glub   = (const float*)d_in[14];
    const float* ln2g   = (const float*)d_in[15];
    const float* ln2b   = (const float*)d_in[16];
    const float* ff2aW  = (const float*)d_in[17];
    const float* ff2ab  = (const float*)d_in[18];
    const float* ff2bW  = (const float*)d_in[19];
    const float* ff2bb  = (const float*)d_in[20];
    float* out = (float*)d_out;

    char* ws = (char*)d_ws;
    float* P   = (float*)(ws);
    float* mu1 = (float*)(ws + (1u << 20));
    float* rs1 = (float*)(ws + (1u << 20) + 262144);
    float* mu2 = (float*)(ws + (1u << 20) + 2 * 262144);
    float* rs2 = (float*)(ws + (1u << 20) + 3 * 262144);
    float* S0  = (float*)(ws + (size_t)(8u << 20));                    // 64MB slot
    float* S1  = (float*)(ws + (size_t)(8u << 20) + (size_t)(64u << 20));

    dim3 gGemm(64, 4, BN);   // T/128 tiles, 256/64 row tiles, batch

    // SSM constants
    prep_kernel<<<64, 64, 0, stream>>>(log_dt, C_re, C_im, logAr, A_im, P);
    // LN1 stats
    ln_stats_kernel<<<dim3(32, BN), 256, 0, stream>>>(x, mu1, rs1);
    // S4D scan (LN1 inline) -> gelu(u) in S0
    scan_kernel<<<512, 256, 0, stream>>>(x, mu1, rs1, ln1g, ln1b, Dp, P, S0);
    // out_W: GLU + gelu -> S1   (= gelu(y2))
    conv1x1_kernel<256, true, false, false, true, false><<<gGemm, 256, 0, stream>>>(
        S0, nullptr, outW, outB, nullptr, nullptr, nullptr, nullptr, nullptr, S1);
    // lin1: plain -> S0 (= y3)
    conv1x1_kernel<256, false, false, false, false, false><<<gGemm, 256, 0, stream>>>(
        S1, nullptr, lin1W, lin1b, nullptr, nullptr, nullptr, nullptr, nullptr, S0);
    // glu_W on concat(x, y3): GLU + residual x -> S1 (= A)
    conv1x1_kernel<512, true, true, false, false, true><<<gGemm, 256, 0, stream>>>(
        x, S0, gluW, glub, nullptr, nullptr, nullptr, nullptr, x, S1);
    // LN2 stats on A
    ln_stats_kernel<<<dim3(32, BN), 256, 0, stream>>>(S1, mu2, rs2);
    // ff2a with inline LN2 + gelu -> S0 (= t1)
    conv1x1_kernel<256, false, false, true, true, false><<<gGemm, 256, 0, stream>>>(
        S1, nullptr, ff2aW, ff2ab, mu2, rs2, ln2g, ln2b, nullptr, S0);
    // ff2b + residual A -> out
    conv1x1_kernel<256, false, false, false, false, true><<<gGemm, 256, 0, stream>>>(
        S0, nullptr, ff2bW, ff2bb, nullptr, nullptr, nullptr, nullptr, S1, out);
}

// Round 2
// 438.388 us; speedup vs baseline: 2.5188x; 2.5188x over previous
//
#include <hip/hip_runtime.h>
#include <math.h>

// S4D block, MI355X round 2: bf16 MFMA GEMMs, channels-last activations.
// B=8, H=256, T=8192, N=16 complex states.

#define TN 8192
#define HN 256
#define BN 8
#define NS 16

typedef __bf16 bf16x8 __attribute__((ext_vector_type(8)));
typedef __bf16 bf16x4 __attribute__((ext_vector_type(4)));
typedef __bf16 bf16x2 __attribute__((ext_vector_type(2)));
typedef float  f32x4  __attribute__((ext_vector_type(4)));

__device__ __forceinline__ float gelu_f(float v) {
    return 0.5f * v * (1.f + erff(v * 0.70710678118654752440f));
}
__device__ __forceinline__ float sigm_f(float v) {
    return 1.f / (1.f + expf(-v));
}

// ---------------- SSM constant prep ----------------
__global__ void prep_kernel(const float* __restrict__ log_dt,
                            const float* __restrict__ C_re,
                            const float* __restrict__ C_im,
                            const float* __restrict__ log_A_real,
                            const float* __restrict__ A_imag,
                            float* __restrict__ P)
{
    int i = blockIdx.x * 64 + threadIdx.x;   // 0..4095
    int h = i >> 4;
    float dt = expf(log_dt[h]);
    float Ar = -expf(log_A_real[i]);
    float Ai = A_imag[i];
    float er = expf(Ar * dt);
    float ar = er * cosf(Ai * dt);
    float ai = er * sinf(Ai * dt);
    float Er = ar - 1.f, Ei = ai;
    float inv = 1.f / (Ar * Ar + Ai * Ai);
    float Fr = (Er * Ar + Ei * Ai) * inv;
    float Fi = (Ei * Ar - Er * Ai) * inv;
    float cr = C_re[i] * Fr - C_im[i] * Fi;
    float ci = C_re[i] * Fi + C_im[i] * Fr;
    float pr = ar, pi = ai;
    #pragma unroll
    for (int s = 0; s < 7; ++s) { float t2 = pr * pr - pi * pi; pi = 2.f * pr * pi; pr = t2; }
    P[i]           = ar;
    P[4096 + i]    = ai;
    P[2*4096 + i]  = 2.f * cr;
    P[3*4096 + i]  = 2.f * ci;
    P[4*4096 + i]  = pr;
    P[5*4096 + i]  = pi;
}

// ---------------- weight prep: fp32 -> bf16, tiled+swizzled LDS image ----------------
// Image: chunks [mt][kt] of 16KB; slot (r,s) holds Wint[mt*128+r][kt*64 + (s^(r&7))*8 .. +8]
// glu: interleave rows (c, c+256) -> (2c, 2c+1)
__global__ void prep_w_kernel(const float* __restrict__ W, __bf16* __restrict__ Wp,
                              int K, int glu)
{
    int id = blockIdx.x * 256 + threadIdx.x;
    int nK = K >> 6;
    int c = id >> 10, r = (id >> 3) & 127, s = id & 7;
    int mt = c / nK, kt = c - mt * nK;
    int R = mt * 128 + r;
    int row = glu ? ((R & 1) ? (R >> 1) + 256 : (R >> 1)) : R;
    int k = kt * 64 + ((s ^ (r & 7)) << 3);
    const float* src = W + (size_t)row * K + k;
    __bf16 o[8];
    #pragma unroll
    for (int j = 0; j < 8; ++j) o[j] = (__bf16)src[j];
    *(uint4*)(Wp + (size_t)id * 8) = *(uint4*)o;
}

// ---------------- channel-LN stats for [B][H][T] fp32 ----------------
__global__ __launch_bounds__(256) void ln_stats_kernel(const float* __restrict__ X,
                                                       float* __restrict__ mu,
                                                       float* __restrict__ rs)
{
    int b = blockIdx.y;
    int t = blockIdx.x * 256 + threadIdx.x;
    const float* p = X + (size_t)b * HN * TN + t;
    float s = 0.f, ss = 0.f;
    #pragma unroll 8
    for (int c = 0; c < HN; ++c) {
        float v = p[(size_t)c * TN];
        s += v; ss += v * v;
    }
    float m = s * (1.f / HN);
    float var = ss * (1.f / HN) - m * m;
    mu[b * TN + t] = m;
    rs[b * TN + t] = rsqrtf(var + 1e-5f);
}

// ---------------- channel-LN stats for [B][T][H] fp32 (channels-last) ----------------
__global__ __launch_bounds__(256) void ln_stats_cl_kernel(const float* __restrict__ A,
                                                          float* __restrict__ mu,
                                                          float* __restrict__ rs)
{
    int row = blockIdx.x * 4 + (threadIdx.x >> 6);   // b*T + t
    int l = threadIdx.x & 63;
    float4 v = *(const float4*)(A + ((size_t)row << 8) + l * 4);
    float s  = v.x + v.y + v.z + v.w;
    float ss = v.x*v.x + v.y*v.y + v.z*v.z + v.w*v.w;
    #pragma unroll
    for (int d = 32; d; d >>= 1) { s += __shfl_down(s, d, 64); ss += __shfl_down(ss, d, 64); }
    if (l == 0) {
        float m = s * (1.f / 256.f);
        mu[row] = m;
        rs[row] = rsqrtf(ss * (1.f / 256.f) - m * m + 1e-5f);
    }
}

// ---------------- transpose [B][H][T] (f32 or bf16) -> [B][T][H] bf16 ----------------
template<typename TI>
__global__ __launch_bounds__(256) void transpose_kernel(const TI* __restrict__ in,
                                                        __bf16* __restrict__ out)
{
    __shared__ float tile[64][65];
    int b = blockIdx.z, h0 = blockIdx.y * 64, t0 = blockIdx.x * 64;
    int tid = threadIdx.x;
    int hl = tid >> 2, pr = tid & 3;
    const TI* src = in + ((size_t)(b * HN + h0 + hl)) * TN + t0 + pr * 16;
    if constexpr (sizeof(TI) == 4) {
        #pragma unroll
        for (int j = 0; j < 4; ++j) {
            float4 v = *(const float4*)((const float*)src + j * 4);
            *(float4*)&tile[hl][pr * 16 + j * 4] = v;
        }
    } else {
        #pragma unroll
        for (int p = 0; p < 2; ++p) {
            bf16x8 v = *(const bf16x8*)((const __bf16*)src + p * 8);
            #pragma unroll
            for (int j = 0; j < 8; ++j) tile[hl][pr * 16 + p * 8 + j] = (float)v[j];
        }
    }
    __syncthreads();
    int tl = tid >> 2;
    __bf16 o[16];
    #pragma unroll
    for (int j = 0; j < 16; ++j) o[j] = (__bf16)tile[pr * 16 + j][tl];
    __bf16* dst = out + ((size_t)(b * TN + t0 + tl)) * HN + h0 + pr * 16;
    *(uint4*)dst = *(uint4*)&o[0];
    *(uint4*)(dst + 8) = *(uint4*)&o[8];
}

// ---------------- S4D recurrence scan (LN1 inline), bf16 out [B][H][T] ----------------
__global__ __launch_bounds__(256) void scan_kernel(const float* __restrict__ X,
                                                   const float* __restrict__ mu,
                                                   const float* __restrict__ rs,
                                                   const float* __restrict__ g1,
                                                   const float* __restrict__ b1,
                                                   const float* __restrict__ Dp,
                                                   const float* __restrict__ P,
                                                   __bf16* __restrict__ GU)
{
    int wid  = (blockIdx.x << 2) + (threadIdx.x >> 6);
    int lane = threadIdx.x & 63;
    int b = wid >> 8, h = wid & 255;

    float ar[NS], ai[NS];
    #pragma unroll
    for (int n = 0; n < NS; ++n) {
        int idx = h * NS + n;
        ar[n] = P[idx];
        ai[n] = P[4096 + idx];
    }
    float gh = g1[h], bh = b1[h];

    const float* xrow = X + (size_t)(b * HN + h) * TN;
    const float* mup  = mu + b * TN;
    const float* rsp  = rs + b * TN;
    int t0 = lane * 128;

    float sr[NS], si[NS];
    #pragma unroll
    for (int n = 0; n < NS; ++n) { sr[n] = 0.f; si[n] = 0.f; }

    for (int j = 0; j < 128; j += 4) {
        float4 xv = *(const float4*)(xrow + t0 + j);
        float4 m4 = *(const float4*)(mup + t0 + j);
        float4 r4 = *(const float4*)(rsp + t0 + j);
        float ys[4];
        ys[0] = fmaf((xv.x - m4.x) * r4.x, gh, bh);
        ys[1] = fmaf((xv.y - m4.y) * r4.y, gh, bh);
        ys[2] = fmaf((xv.z - m4.z) * r4.z, gh, bh);
        ys[3] = fmaf((xv.w - m4.w) * r4.w, gh, bh);
        #pragma unroll
        for (int e = 0; e < 4; ++e) {
            float y = ys[e];
            #pragma unroll
            for (int n = 0; n < NS; ++n) {
                float nr = fmaf(ar[n], sr[n], fmaf(-ai[n], si[n], y));
                float ni = fmaf(ar[n], si[n], ai[n] * sr[n]);
                sr[n] = nr; si[n] = ni;
            }
        }
    }

    float pdr[NS], pdi[NS];
    #pragma unroll
    for (int n = 0; n < NS; ++n) {
        int idx = h * NS + n;
        pdr[n] = P[4*4096 + idx];
        pdi[n] = P[5*4096 + idx];
    }
    #pragma unroll
    for (int d = 1; d < 64; d <<= 1) {
        #pragma unroll
        for (int n = 0; n < NS; ++n) {
            float qpr = __shfl_up(sr[n], (unsigned)d, 64);
            float qpi = __shfl_up(si[n], (unsigned)d, 64);
            if (lane >= d) {
                float nqr = fmaf(pdr[n], qpr, fmaf(-pdi[n], qpi, sr[n]));
                float nqi = fmaf(pdr[n], qpi, fmaf(pdi[n], qpr, si[n]));
                sr[n] = nqr; si[n] = nqi;
            }
        }
        #pragma unroll
        for (int n = 0; n < NS; ++n) {
            float t2 = pdr[n] * pdr[n] - pdi[n] * pdi[n];
            pdi[n] = 2.f * pdr[n] * pdi[n];
            pdr[n] = t2;
        }
    }
    #pragma unroll
    for (int n = 0; n < NS; ++n) {
        float ir = __shfl_up(sr[n], 1u, 64);
        float ii = __shfl_up(si[n], 1u, 64);
        sr[n] = (lane == 0) ? 0.f : ir;
        si[n] = (lane == 0) ? 0.f : ii;
    }

    float c2r[NS], c2i[NS];
    #pragma unroll
    for (int n = 0; n < NS; ++n) {
        int idx = h * NS + n;
        c2r[n] = P[2*4096 + idx];
        c2i[n] = P[3*4096 + idx];
    }
    float dh = Dp[h];
    __bf16* gout = GU + (size_t)(b * HN + h) * TN;
    for (int j = 0; j < 128; j += 4) {
        float4 xv = *(const float4*)(xrow + t0 + j);
        float4 m4 = *(const float4*)(mup + t0 + j);
        float4 r4 = *(const float4*)(rsp + t0 + j);
        float ys[4];
        ys[0] = fmaf((xv.x - m4.x) * r4.x, gh, bh);
        ys[1] = fmaf((xv.y - m4.y) * r4.y, gh, bh);
        ys[2] = fmaf((xv.z - m4.z) * r4.z, gh, bh);
        ys[3] = fmaf((xv.w - m4.w) * r4.w, gh, bh);
        __bf16 ov[4];
        #pragma unroll
        for (int e = 0; e < 4; ++e) {
            float y = ys[e];
            float u = dh * y;
            #pragma unroll
            for (int n = 0; n < NS; ++n) {
                float nr = fmaf(ar[n], sr[n], fmaf(-ai[n], si[n], y));
                float ni = fmaf(ar[n], si[n], ai[n] * sr[n]);
                sr[n] = nr; si[n] = ni;
                u = fmaf(c2r[n], nr, fmaf(-c2i[n], ni, u));
            }
            ov[e] = (__bf16)gelu_f(u);
        }
        *(bf16x4*)(gout + t0 + j) = *(bf16x4*)ov;
    }
}

// ---------------- MFMA conv1x1 GEMM, channels-last ----------------
// out[m][t] = epi( sum_k Wint[m][k] * Xcl[b][t][k] + bias )
// Tile 128m x 128t x 64k, 4 waves 2x2, each wave 64x64 via 4x4 16x16x32 MFMAs.
// A staged from pre-swizzled weight image (linear global_load_lds).
// B staged via global_load_lds with pre-swizzled per-lane global address,
// or reg-staged with inline LN + f32->bf16 when LNIN.
// OMODE 0: bf16 out [B][T][H];  1: fp32 A_cl [B][T][H] += x ([B][H][T]);
// OMODE 2: fp32 out [B][H][T] += resF (fp32 [B][T][H]).
template<int K, bool GLU, bool CONCAT, bool LNIN, bool GELUOUT, int OMODE>
__global__ __launch_bounds__(256) void gemm_cl_kernel(
    const __bf16* __restrict__ B0, const __bf16* __restrict__ B1,
    const float*  __restrict__ BF,
    const __bf16* __restrict__ Wp, const float* __restrict__ bias,
    const float* __restrict__ mu, const float* __restrict__ rsd,
    const float* __restrict__ lng, const float* __restrict__ lnb,
    const float* __restrict__ resF, float* __restrict__ outF,
    __bf16* __restrict__ outB)
{
    constexpr int nK = K / 64;
    __shared__ __align__(16) char lds[32768];
    char* sA = lds;
    char* sB = lds + 16384;
    int tid = threadIdx.x;
    int w = tid >> 6, wr = w >> 1, wc = w & 1;
    int b = blockIdx.z, by = blockIdx.y;
    int t0 = blockIdx.x * 128;
    int lane = tid & 63;
    int lr = tid & 15, lg = (tid >> 4) & 3;
    int rl = lane >> 3, sl = lane & 7;

    f32x4 acc[4][4];
    #pragma unroll
    for (int i = 0; i < 4; ++i)
        #pragma unroll
        for (int j = 0; j < 4; ++j) acc[i][j] = (f32x4){0.f, 0.f, 0.f, 0.f};

    for (int kt = 0; kt < nK; ++kt) {
        // ---- stage A (16KB pre-swizzled chunk, linear copy) ----
        {
            const char* asrc = (const char*)Wp + (((size_t)by * nK + kt) << 14)
                               + w * 4096 + lane * 16;
            char* adst = sA + w * 4096;
            #pragma unroll
            for (int i = 0; i < 4; ++i)
                __builtin_amdgcn_global_load_lds(
                    (const __attribute__((address_space(1))) void*)(asrc + i * 1024),
                    (__attribute__((address_space(3))) void*)(adst + i * 1024), 16, 0, 0);
        }
        // ---- stage B ----
        if constexpr (!LNIN) {
            int kg = kt * 64;
            const __bf16* base = (CONCAT && kg >= 256) ? B1 : B0;
            int kloc = (CONCAT && kg >= 256) ? kg - 256 : kg;
            #pragma unroll
            for (int i = 0; i < 4; ++i) {
                int rb = w * 32 + i * 8 + rl;
                const char* gs = (const char*)(base + (((size_t)(b * TN + t0 + rb)) << 8) + kloc)
                                 + ((sl ^ rl) << 4);
                __builtin_amdgcn_global_load_lds(
                    (const __attribute__((address_space(1))) void*)gs,
                    (__attribute__((address_space(3))) void*)(sB + w * 4096 + i * 1024), 16, 0, 0);
            }
        } else {
            #pragma unroll
            for (int i = 0; i < 8; ++i) {
                int q = i * 256 + tid;
                int r = q >> 4, qs = q & 15;
                int t = t0 + r;
                const float* src = BF + (((size_t)(b * TN + t)) << 8) + kt * 64 + qs * 4;
                float4 v = *(const float4*)src;
                float m_ = mu[b * TN + t], rr = rsd[b * TN + t];
                float4 g4 = *(const float4*)(lng + kt * 64 + qs * 4);
                float4 b4 = *(const float4*)(lnb + kt * 64 + qs * 4);
                __bf16 o[4];
                o[0] = (__bf16)fmaf((v.x - m_) * rr, g4.x, b4.x);
                o[1] = (__bf16)fmaf((v.y - m_) * rr, g4.y, b4.y);
                o[2] = (__bf16)fmaf((v.z - m_) * rr, g4.z, b4.z);
                o[3] = (__bf16)fmaf((v.w - m_) * rr, g4.w, b4.w);
                int off = r * 128 + ((((qs >> 1) ^ (r & 7))) << 4) + (qs & 1) * 8;
                *(uint2*)(sB + off) = *(uint2*)o;
            }
        }
        __syncthreads();

        // ---- MFMA ----
        const char* aB = sA + (wr * 64 + lr) * 128;
        const char* bB = sB + (wc * 64 + lr) * 128;
        int swz = (lr & 7) << 4;
        #pragma unroll
        for (int ks = 0; ks < 2; ++ks) {
            int ko = (ks * 64 + lg * 16) ^ swz;
            bf16x8 af[4], bfr[4];
            #pragma unroll
            for (int f = 0; f < 4; ++f) af[f]  = *(const bf16x8*)(aB + f * 2048 + ko);
            #pragma unroll
            for (int f = 0; f < 4; ++f) bfr[f] = *(const bf16x8*)(bB + f * 2048 + ko);
            #pragma unroll
            for (int fm = 0; fm < 4; ++fm)
                #pragma unroll
                for (int fn = 0; fn < 4; ++fn)
                    acc[fm][fn] = __builtin_amdgcn_mfma_f32_16x16x32_bf16(
                        af[fm], bfr[fn], acc[fm][fn], 0, 0, 0);
        }
        __syncthreads();
    }

    // ---- epilogue ----
    int tcb = t0 + wc * 64 + lr;
    int mrow0 = by * 128 + wr * 64 + lg * 4;
    #pragma unroll
    for (int fm = 0; fm < 4; ++fm) {
        int R0 = mrow0 + fm * 16;
        #pragma unroll
        for (int fn = 0; fn < 4; ++fn) {
            int t = tcb + fn * 16;
            f32x4 v = acc[fm][fn];
            size_t rowoff = ((size_t)(b * TN + t)) << 8;
            if constexpr (GLU) {
                int c_ = R0 >> 1;
                float a0 = v[0] + bias[c_],     g0 = v[1] + bias[c_ + 256];
                float a1 = v[2] + bias[c_ + 1], g1 = v[3] + bias[c_ + 257];
                float o0 = a0 * sigm_f(g0), o1 = a1 * sigm_f(g1);
                if constexpr (GELUOUT) { o0 = gelu_f(o0); o1 = gelu_f(o1); }
                if constexpr (OMODE == 0) {
                    bf16x2 ov; ov[0] = (__bf16)o0; ov[1] = (__bf16)o1;
                    *(bf16x2*)(outB + rowoff + c_) = ov;
                } else {  // OMODE 1: A = x + z (x is [B][H][T] fp32)
                    float x0 = resF[((size_t)(b * HN + c_))     * TN + t];
                    float x1 = resF[((size_t)(b * HN + c_ + 1)) * TN + t];
                    float2 ov = make_float2(o0 + x0, o1 + x1);
                    *(float2*)(outF + rowoff + c_) = ov;
                }
            } else {
                float vv[4];
                #pragma unroll
                for (int j = 0; j < 4; ++j) vv[j] = v[j] + bias[R0 + j];
                if constexpr (GELUOUT) {
                    #pragma unroll
                    for (int j = 0; j < 4; ++j) vv[j] = gelu_f(vv[j]);
                }
                if constexpr (OMODE == 0) {
                    bf16x4 ov;
                    #pragma unroll
                    for (int j = 0; j < 4; ++j) ov[j] = (__bf16)vv[j];
                    *(bf16x4*)(outB + rowoff + R0) = ov;
                } else {  // OMODE 2: fp32 [B][H][T] out, += resF (cl)
                    float4 rv = *(const float4*)(resF + rowoff + R0);
                    float rr4[4] = {rv.x, rv.y, rv.z, rv.w};
                    #pragma unroll
                    for (int j = 0; j < 4; ++j)
                        outF[((size_t)(b * HN + R0 + j)) * TN + t] = vv[j] + rr4[j];
                }
            }
        }
    }
}

extern "C" void kernel_launch(void* const* d_in, const int* in_sizes, int n_in,
                              void* d_out, int out_size, void* d_ws, size_t ws_size,
                              hipStream_t stream)
{
    (void)in_sizes; (void)n_in; (void)out_size; (void)ws_size;
    const float* x      = (const float*)d_in[0];
    const float* log_dt = (const float*)d_in[1];
    const float* C_re   = (const float*)d_in[2];
    const float* C_im   = (const float*)d_in[3];
    const float* logAr  = (const float*)d_in[4];
    const float* A_im   = (const float*)d_in[5];
    const float* Dp     = (const float*)d_in[6];
    const float* outW   = (const float*)d_in[7];
    const float* outB   = (const float*)d_in[8];
    const float* ln1g   = (const float*)d_in[9];
    const float* ln1b   = (const float*)d_in[10];
    const float* lin1W  = (const float*)d_in[11];
    const float* lin1b  = (const float*)d_in[12];
    const float* gluW   = (const float*)d_in[13];
    const float* glub   = (const float*)d_in[14];
    const float* ln2g   = (const float*)d_in[15];
    const float* ln2b   = (const float*)d_in[16];
    const float* ff2aW  = (const float*)d_in[17];
    const float* ff2ab  = (const float*)d_in[18];
    const float* ff2bW  = (const float*)d_in[19];
    const float* ff2bb  = (const float*)d_in[20];
    float* out = (float*)d_out;

    char* ws = (char*)d_ws;
    const size_t MB = 1u << 20;
    float*  P    = (float*)(ws);
    float*  mu1  = (float*)(ws + 0x40000);
    float*  rs1  = (float*)(ws + 0x80000);
    float*  mu2  = (float*)(ws + 0xC0000);
    float*  rs2  = (float*)(ws + 0x100000);
    __bf16* WpO  = (__bf16*)(ws + 0x140000);   // outW 512x256 (glu-interleaved) 256KB
    __bf16* WpL  = (__bf16*)(ws + 0x180000);   // lin1 256x256 128KB
    __bf16* WpG  = (__bf16*)(ws + 0x1A0000);   // gluW 512x512 (glu-interleaved) 512KB
    __bf16* WpA  = (__bf16*)(ws + 0x220000);   // ff2a 128KB
    __bf16* WpB  = (__bf16*)(ws + 0x240000);   // ff2b 128KB
    __bf16* x_cl = (__bf16*)(ws + 4 * MB);     // 32MB [B][T][H] bf16
    char*   slB  = ws + 36 * MB;               // 32MB
    char*   slC  = ws + 68 * MB;               // 32MB
    float*  A_cl = (float*)(ws + 68 * MB);     // 64MB fp32 (slC+slD)

    // constants + weight images
    prep_kernel<<<64, 64, 0, stream>>>(log_dt, C_re, C_im, logAr, A_im, P);
    prep_w_kernel<<<64, 256, 0, stream>>>(outW,  WpO, 256, 1);
    prep_w_kernel<<<32, 256, 0, stream>>>(lin1W, WpL, 256, 0);
    prep_w_kernel<<<128, 256, 0, stream>>>(gluW, WpG, 512, 1);
    prep_w_kernel<<<32, 256, 0, stream>>>(ff2aW, WpA, 256, 0);
    prep_w_kernel<<<32, 256, 0, stream>>>(ff2bW, WpB, 256, 0);

    // LN1 stats; x -> channels-last bf16
    ln_stats_kernel<<<dim3(32, BN), 256, 0, stream>>>(x, mu1, rs1);
    transpose_kernel<float><<<dim3(128, 4, BN), 256, 0, stream>>>(x, x_cl);

    // scan -> gu bf16 [B][H][T] (slC), then transpose -> gu_cl (slB)
    __bf16* gu_raw = (__bf16*)slC;
    __bf16* gu_cl  = (__bf16*)slB;
    scan_kernel<<<512, 256, 0, stream>>>(x, mu1, rs1, ln1g, ln1b, Dp, P, gu_raw);
    transpose_kernel<__bf16><<<dim3(128, 4, BN), 256, 0, stream>>>(gu_raw, gu_cl);

    dim3 g2(64, 2, BN), g4(64, 4, BN);
    __bf16* y2g = (__bf16*)slC;   // gelu(GLU(outW...)) overwrites gu_raw slot
    __bf16* y3  = (__bf16*)slB;   // overwrites gu_cl slot
    __bf16* t1  = (__bf16*)slB;   // overwrites y3 slot after GEMM3

    // GEMM1: y2g = gelu(GLU(outW · gu + outB))
    gemm_cl_kernel<256, true, false, false, true, 0><<<g4, 256, 0, stream>>>(
        gu_cl, nullptr, nullptr, WpO, outB, nullptr, nullptr, nullptr, nullptr,
        nullptr, nullptr, y2g);
    // GEMM2: y3 = lin1 · y2g + lin1b
    gemm_cl_kernel<256, false, false, false, false, 0><<<g2, 256, 0, stream>>>(
        y2g, nullptr, nullptr, WpL, lin1b, nullptr, nullptr, nullptr, nullptr,
        nullptr, nullptr, y3);
    // GEMM3: A_cl = x + GLU(gluW · [x_cl; y3] + glub)   (fp32 cl)
    gemm_cl_kernel<512, true, true, false, false, 1><<<g4, 256, 0, stream>>>(
        x_cl, y3, nullptr, WpG, glub, nullptr, nullptr, nullptr, nullptr,
        x, A_cl, nullptr);
    // LN2 stats on A_cl
    ln_stats_cl_kernel<<<16384, 256, 0, stream>>>(A_cl, mu2, rs2);
    // GEMM4: t1 = gelu(ff2a · LN2(A) + ff2ab)
    gemm_cl_kernel<256, false, false, true, true, 0><<<g2, 256, 0, stream>>>(
        nullptr, nullptr, A_cl, WpA, ff2ab, mu2, rs2, ln2g, ln2b,
        nullptr, nullptr, t1);
    // GEMM5: out = A + ff2b · t1 + ff2bb   (fp32 [B][H][T])
    gemm_cl_kernel<256, false, false, false, false, 2><<<g2, 256, 0, stream>>>(
        t1, nullptr, nullptr, WpB, ff2bb, nullptr, nullptr, nullptr, nullptr,
        A_cl, out, nullptr);
}